// Round 6
// baseline (196.888 us; speedup 1.0000x reference)
//
#include <hip/hip_runtime.h>
#include <hip/hip_fp16.h>
#include <stdint.h>

#define NN 100000
#define NB 512
#define BUCKET 196   // ceil(NN/NB)
#define TILE 4096
#define EPT 16       // TILE / 256

typedef _Float16 f16x8 __attribute__((ext_vector_type(8)));
typedef float f32x4  __attribute__((ext_vector_type(4)));

__device__ __forceinline__ int edge_at(const void* p, int f64, long long idx){
    return f64 ? (int)((const long long*)p)[idx] : ((const int*)p)[idx];
}

// ---------- graph preprocessing ----------

__global__ void k_detect(const void* __restrict__ ep, int* flag, long long nwords, long long nn){
    __shared__ int bad;
    if (threadIdx.x == 0) bad = 0;
    __syncthreads();
    const long long* p = (const long long*)ep;
    for (long long i = threadIdx.x; i < 1024 && i < nwords; i += blockDim.x){
        long long v = p[i];
        if (v < 0 || v >= nn) atomicOr(&bad, 1);
    }
    __syncthreads();
    if (threadIdx.x == 0) flag[0] = bad ? 0 : 1;  // 1 => int64
}

__global__ __launch_bounds__(256) void k_hist(const void* __restrict__ ep, const int* __restrict__ flag,
                                              int* __restrict__ gbcnt, int E){
    __shared__ int h[NB];
    for (int i = threadIdx.x; i < NB; i += 256) h[i] = 0;
    __syncthreads();
    int f = flag[0];
    for (long long e = blockIdx.x * 256 + threadIdx.x; e < E; e += (long long)gridDim.x * 256){
        int d = edge_at(ep, f, (long long)E + e);
        atomicAdd(&h[d / BUCKET], 1);
    }
    __syncthreads();
    for (int i = threadIdx.x; i < NB; i += 256)
        if (h[i]) atomicAdd(&gbcnt[i], h[i]);
}

__global__ void k_scanB(const int* __restrict__ gbcnt, int* __restrict__ bbase,
                        int* __restrict__ bcursor, int E){
    __shared__ int sh[NB];
    int t = threadIdx.x;
    int own = gbcnt[t];
    sh[t] = own; __syncthreads();
    for (int off = 1; off < NB; off <<= 1){
        int u = (t >= off) ? sh[t - off] : 0;
        __syncthreads();
        sh[t] += u;
        __syncthreads();
    }
    int excl = sh[t] - own;
    bbase[t] = excl;
    bcursor[t] = excl;
    if (t == NB - 1) bbase[NB] = excl + own;
    (void)E;
}

__global__ __launch_bounds__(256) void k_scatter(const void* __restrict__ ep, const int* __restrict__ flag,
                                                 int* __restrict__ bcursor, uint2* __restrict__ rec, int E){
    __shared__ int h[NB];
    __shared__ int gb[NB];
    int f = flag[0];
    long long base = (long long)blockIdx.x * TILE;
    for (int i = threadIdx.x; i < NB; i += 256) h[i] = 0;
    __syncthreads();
    int s[EPT], d[EPT], r[EPT], bb[EPT];
    #pragma unroll
    for (int j = 0; j < EPT; ++j){
        long long e = base + j * 256 + threadIdx.x;
        if (e < E){
            s[j]  = edge_at(ep, f, e);
            d[j]  = edge_at(ep, f, (long long)E + e);
            bb[j] = d[j] / BUCKET;
            r[j]  = atomicAdd(&h[bb[j]], 1);
        }
    }
    __syncthreads();
    for (int i = threadIdx.x; i < NB; i += 256)
        gb[i] = h[i] ? atomicAdd(&bcursor[i], h[i]) : 0;
    __syncthreads();
    #pragma unroll
    for (int j = 0; j < EPT; ++j){
        long long e = base + j * 256 + threadIdx.x;
        if (e < E) rec[gb[bb[j]] + r[j]] = make_uint2((unsigned)s[j], (unsigned)d[j]);
    }
}

__global__ __launch_bounds__(256) void k_csr(const uint2* __restrict__ rec, const int* __restrict__ bbase,
                                             int* __restrict__ rp, int* __restrict__ col,
                                             float* __restrict__ dinv, int E){
    int b = blockIdx.x;
    int t = threadIdx.x;
    if (b == 0 && t == 0) rp[NN] = E;
    int d0 = b * BUCKET;
    if (d0 >= NN) return;
    int e0 = bbase[b], e1 = bbase[b + 1];
    __shared__ int h[BUCKET];
    __shared__ int sc[256];
    __shared__ int cur[BUCKET];
    for (int i = t; i < BUCKET; i += 256) h[i] = 0;
    __syncthreads();
    for (int e = e0 + t; e < e1; e += 256)
        atomicAdd(&h[rec[e].y - d0], 1);
    __syncthreads();
    int own = (t < BUCKET) ? h[t] : 0;
    sc[t] = own; __syncthreads();
    for (int off = 1; off < 256; off <<= 1){
        int u = (t >= off) ? sc[t - off] : 0;
        __syncthreads();
        sc[t] += u;
        __syncthreads();
    }
    int excl = sc[t] - own;
    if (t < BUCKET && d0 + t < NN){
        rp[d0 + t]   = e0 + excl;
        cur[t]       = e0 + excl;
        dinv[d0 + t] = rsqrtf((float)(own + 1));
    }
    __syncthreads();
    for (int e = e0 + t; e < e1; e += 256){
        uint2 u = rec[e];
        int p = atomicAdd(&cur[u.y - d0], 1);
        col[p] = (int)u.x;
    }
}

// ---------- GEMM1 via fp16 MFMA, direct-from-global A fragments ----------

// Pack W1 (165x128 fp32, zero-padded K to 192) into fragment-ready fp16.
// Rows k>=165 are ZERO -> A-fragment garbage at k>=165 multiplies zero.
__global__ __launch_bounds__(256) void k_prepW(const float* __restrict__ W1, _Float16* __restrict__ Bf){
    int q = blockIdx.x * 256 + threadIdx.x;   // 192*128 = 24576
    if (q >= 192 * 128) return;
    int k = q >> 7, c = q & 127;
    float w = (k < 165) ? W1[k * 128 + c] : 0.0f;
    int tt = k >> 5, kk = k & 31;
    int lane = ((kk >> 3) << 4) + (c & 15);
    int j = kk & 7;
    int f = c >> 4;
    int idx = (((tt * 8 + f) * 64 + lane) << 3) + j;
    Bf[idx] = (_Float16)w;
}

// C = (x @ W1) * dinv, stored fp16. 64 rows x 128 cols per block, no LDS, no barrier.
// Wave w owns cols [32w,32w+32). A frags loaded as 8 independent scalar fp32 loads.
__global__ __launch_bounds__(256) void k_gemm1(const float* __restrict__ x,
                                               const _Float16* __restrict__ Bf16,
                                               const float* __restrict__ dinv,
                                               _Float16* __restrict__ xws, int n){
    int t = threadIdx.x;
    int w = t >> 6, lane = t & 63;
    int i0 = blockIdx.x * 64;
    int rl = lane & 15, kl = (lane >> 4) * 8;

    f16x8 Bf[6][2];
    #pragma unroll
    for (int tt = 0; tt < 6; ++tt)
        #pragma unroll
        for (int cf = 0; cf < 2; ++cf)
            Bf[tt][cf] = *(const f16x8*)&Bf16[((tt * 8 + (w * 2 + cf)) * 64 + lane) << 3];

    f32x4 acc[4][2];
    #pragma unroll
    for (int m = 0; m < 4; ++m){ acc[m][0] = (f32x4)0.0f; acc[m][1] = (f32x4)0.0f; }

    if (i0 + 64 < n){
        // fast path: rows all valid; k-overrun reads neighbor-row floats (benign, B pad = 0)
        #pragma unroll
        for (int tt = 0; tt < 6; ++tt){
            f16x8 ah[4];
            #pragma unroll
            for (int m = 0; m < 4; ++m){
                const float* xr = x + (size_t)(i0 + m * 16 + rl) * 165 + tt * 32 + kl;
                #pragma unroll
                for (int j = 0; j < 8; ++j)
                    ah[m][j] = (_Float16)xr[j];
            }
            #pragma unroll
            for (int m = 0; m < 4; ++m)
                #pragma unroll
                for (int cf = 0; cf < 2; ++cf)
                    acc[m][cf] = __builtin_amdgcn_mfma_f32_16x16x32_f16(ah[m], Bf[tt][cf], acc[m][cf], 0, 0, 0);
        }
    } else {
        // tail blocks: fully guarded
        #pragma unroll
        for (int tt = 0; tt < 6; ++tt){
            f16x8 ah[4];
            #pragma unroll
            for (int m = 0; m < 4; ++m){
                int row = i0 + m * 16 + rl;
                int kb = tt * 32 + kl;
                const float* xr = x + (size_t)row * 165 + kb;
                bool rok = row < n;
                #pragma unroll
                for (int j = 0; j < 8; ++j)
                    ah[m][j] = (_Float16)((rok && (kb + j) < 165) ? xr[j] : 0.0f);
            }
            #pragma unroll
            for (int m = 0; m < 4; ++m)
                #pragma unroll
                for (int cf = 0; cf < 2; ++cf)
                    acc[m][cf] = __builtin_amdgcn_mfma_f32_16x16x32_f16(ah[m], Bf[tt][cf], acc[m][cf], 0, 0, 0);
        }
    }

    // epilogue: C row=(lane>>4)*4+r, col=lane&15 within each 16x16 tile; store fp16
    #pragma unroll
    for (int m = 0; m < 4; ++m){
        int rbase = i0 + m * 16 + (lane >> 4) * 4;
        float dv[4];
        #pragma unroll
        for (int r = 0; r < 4; ++r)
            dv[r] = (rbase + r < n) ? dinv[rbase + r] : 0.0f;
        #pragma unroll
        for (int cf = 0; cf < 2; ++cf){
            int colg = w * 32 + cf * 16 + (lane & 15);
            #pragma unroll
            for (int r = 0; r < 4; ++r){
                int row = rbase + r;
                if (row < n)
                    xws[(size_t)row * 128 + colg] = (_Float16)(acc[m][cf][r] * dv[r]);
            }
        }
    }
}

// ---------- SpMM layer 1: wave/node, fp16 packed accumulate, SGPR row bases ----------

__global__ __launch_bounds__(256) void k_spmm1(const __half2* __restrict__ xwh, const int* __restrict__ rp,
                                               const int* __restrict__ col, const float* __restrict__ dinv,
                                               const float* __restrict__ b1, const float* __restrict__ W2,
                                               float* __restrict__ hw2s, int n){
    int wave = (blockIdx.x * 256 + threadIdx.x) >> 6;
    int lane = threadIdx.x & 63;
    if (wave >= n) return;
    int i = wave;
    int e0 = rp[i], e1 = rp[i + 1];
    float di = dinv[i];
    __half2 a = xwh[(size_t)i * 64 + lane];    // self loop
    for (int base = e0; base < e1; base += 64){
        int rem = e1 - base;
        int m = rem < 64 ? rem : 64;
        int c = (lane < m) ? col[base + lane] : 0;
        int j = 0;
        for (; j + 8 <= m; j += 8){
            int s0 = __builtin_amdgcn_readlane(c, j + 0);
            int s1 = __builtin_amdgcn_readlane(c, j + 1);
            int s2 = __builtin_amdgcn_readlane(c, j + 2);
            int s3 = __builtin_amdgcn_readlane(c, j + 3);
            int s4 = __builtin_amdgcn_readlane(c, j + 4);
            int s5 = __builtin_amdgcn_readlane(c, j + 5);
            int s6 = __builtin_amdgcn_readlane(c, j + 6);
            int s7 = __builtin_amdgcn_readlane(c, j + 7);
            __half2 v0 = xwh[(size_t)s0 * 64 + lane];
            __half2 v1 = xwh[(size_t)s1 * 64 + lane];
            __half2 v2 = xwh[(size_t)s2 * 64 + lane];
            __half2 v3 = xwh[(size_t)s3 * 64 + lane];
            __half2 v4 = xwh[(size_t)s4 * 64 + lane];
            __half2 v5 = xwh[(size_t)s5 * 64 + lane];
            __half2 v6 = xwh[(size_t)s6 * 64 + lane];
            __half2 v7 = xwh[(size_t)s7 * 64 + lane];
            __half2 t01 = __hadd2(v0, v1), t23 = __hadd2(v2, v3);
            __half2 t45 = __hadd2(v4, v5), t67 = __hadd2(v6, v7);
            a = __hadd2(a, __hadd2(__hadd2(t01, t23), __hadd2(t45, t67)));
        }
        for (; j < m; ++j){
            int s = __builtin_amdgcn_readlane(c, j);
            a = __hadd2(a, xwh[(size_t)s * 64 + lane]);
        }
    }
    float a0 = __low2float(a), a1 = __high2float(a);
    int f0 = 2 * lane;
    float h0 = fmaxf(di * a0 + b1[f0], 0.0f);
    float h1 = fmaxf(di * a1 + b1[f0 + 1], 0.0f);
    float4 wv = *(const float4*)(W2 + 4 * lane);
    float s0 = h0 * wv.x + h1 * wv.z;
    float s1 = h0 * wv.y + h1 * wv.w;
    #pragma unroll
    for (int off = 32; off > 0; off >>= 1){
        s0 += __shfl_xor(s0, off);
        s1 += __shfl_xor(s1, off);
    }
    if (lane == 0){
        hw2s[2 * i]     = s0 * di;
        hw2s[2 * i + 1] = s1 * di;
    }
}

__global__ __launch_bounds__(256) void k_spmm2(const int* __restrict__ rp, const int* __restrict__ col,
                                               const float* __restrict__ dinv, const float* __restrict__ hw2s,
                                               const float* __restrict__ b2, const float* __restrict__ Wc,
                                               const float* __restrict__ bc, float* __restrict__ out, int n){
    int i = blockIdx.x * 256 + threadIdx.x;
    if (i >= n) return;
    int e0 = rp[i], e1 = rp[i + 1];
    float s0 = hw2s[2 * i], s1 = hw2s[2 * i + 1];
    for (int e = e0; e < e1; ++e){
        int s = col[e];
        s0 += hw2s[2 * s];
        s1 += hw2s[2 * s + 1];
    }
    float di = dinv[i];
    float a0 = fmaxf(di * s0 + b2[0], 0.0f);
    float a1 = fmaxf(di * s1 + b2[1], 0.0f);
    float z = a0 * Wc[0] + a1 * Wc[1] + bc[0];
    out[i] = 1.0f / (1.0f + expf(-z));
}

extern "C" void kernel_launch(void* const* d_in, const int* in_sizes, int n_in,
                              void* d_out, int out_size, void* d_ws, size_t ws_size,
                              hipStream_t stream) {
    const float* x  = (const float*)d_in[0];
    const void*  ei = d_in[1];
    const float* W1 = (const float*)d_in[2];
    const float* b1 = (const float*)d_in[3];
    const float* W2 = (const float*)d_in[4];
    const float* b2 = (const float*)d_in[5];
    const float* Wc = (const float*)d_in[6];
    const float* bc = (const float*)d_in[7];
    float* out = (float*)d_out;

    const int n = NN;
    const int E = in_sizes[1] / 2;

    char* ws = (char*)d_ws;
    size_t off = 0;
    auto alloc = [&](size_t bytes)->char*{
        off = (off + 255) & ~(size_t)255;
        char* p = ws + off; off += bytes; return p;
    };
    int*      flag    = (int*)alloc(4);
    int*      gbcnt   = (int*)alloc((size_t)NB * 4);
    int*      bbase   = (int*)alloc((size_t)(NB + 1) * 4);
    int*      bcursor = (int*)alloc((size_t)NB * 4);
    int*      rp      = (int*)alloc((size_t)(n + 1) * 4);
    float*    dinv    = (float*)alloc((size_t)n * 4);
    float*    hw2s    = (float*)alloc((size_t)n * 2 * 4);
    _Float16* Bf      = (_Float16*)alloc((size_t)192 * 128 * 2);
    int*      col     = (int*)alloc((size_t)E * 4);
    char*     big     = alloc((size_t)n * 128 * 2);   // rec (E*8=12.8MB) aliases xws (25.6MB)
    uint2*    rec     = (uint2*)big;
    _Float16* xws     = (_Float16*)big;
    (void)ws_size; (void)n_in; (void)out_size;

    hipMemsetAsync(gbcnt, 0, (size_t)NB * 4, stream);
    k_detect<<<1, 256, 0, stream>>>(ei, flag, (long long)E, (long long)n);
    k_prepW<<<96, 256, 0, stream>>>(W1, Bf);

    int gN = (n + 255) / 256;
    int gT = (E + TILE - 1) / TILE;

    k_hist<<<256, 256, 0, stream>>>(ei, flag, gbcnt, E);
    k_scanB<<<1, NB, 0, stream>>>(gbcnt, bbase, bcursor, E);
    k_scatter<<<gT, 256, 0, stream>>>(ei, flag, bcursor, rec, E);
    k_csr<<<NB, 256, 0, stream>>>(rec, bbase, rp, col, dinv, E);
    k_gemm1<<<(n + 63) / 64, 256, 0, stream>>>(x, Bf, dinv, xws, n);
    k_spmm1<<<(n * 64 + 255) / 256, 256, 0, stream>>>((const __half2*)xws, rp, col, dinv, b1, W2, hw2s, n);
    k_spmm2<<<gN, 256, 0, stream>>>(rp, col, dinv, hw2s, b2, Wc, bc, out, n);
}